// Round 3
// baseline (105.916 us; speedup 1.0000x reference)
//
#include <hip/hip_runtime.h>

#define IMG_H 224
#define IMG_W 224
#define NPIX (IMG_H * IMG_W)        // 50176
#define NG 1024
#define TILE 8
#define TX_N (IMG_W / TILE)         // 28
#define TY_N (IMG_H / TILE)         // 28
#define NTILE (TX_N * TY_N)         // 784
#define CAP NG                      // per-tile capacity: can never overflow
#define ENT_BYTES 32
#define ENT_STRIDE ((size_t)CAP * ENT_BYTES)   // 32 KiB per tile slab

#define K_EXP  -0.72134752044448170368f   // -0.5 * log2(e)
#define ELIM   -21.640425613334451f       // 30 * K_EXP  (min(dist,30))
#define W15     3.0590232050182579e-07f   // exp(-15) = 2^ELIM

// ws layout:
//   [0, 16)          float S[4]      (sum of a*color over all gaussians)
//   [16, 3152)       int counts[784]
//   [4096, 53248)    GStage gstage[1024]  (48 B each)
//   [65536, ...)     per-tile entry slabs, 32 KiB each
#define WS_S_OFF      0
#define WS_CNT_OFF    16
#define WS_STAGE_OFF  4096
#define WS_ENT_OFF    65536
#define WS_NEED (WS_ENT_OFF + (size_t)NTILE * ENT_STRIDE)   // ~24.6 MiB

struct __align__(16) GParam { float cx, cy, A, B, C, cr, cg, cb; };
struct __align__(16) GStage { GParam q; int tx0, tx1, ty0, ty1; };

// ---------- pass 1: per-gaussian params + bbox + global color sum ----------
__global__ __launch_bounds__(256) void prep_kernel(
    const float* __restrict__ alpha,
    const float* __restrict__ color,
    const float* __restrict__ offset,
    const float* __restrict__ scale,
    const float* __restrict__ rotation,
    const float* __restrict__ basep,
    const float* __restrict__ iw,
    GStage* __restrict__ gs,
    float* __restrict__ S)
{
    const int g = blockIdx.x * 256 + threadIdx.x;
    if (g >= NG) return;
    float cx = fminf(fmaxf(basep[2*g]   + offset[2*g],   0.f), 224.f);
    float cy = fminf(fmaxf(basep[2*g+1] + offset[2*g+1], 0.f), 224.f);
    float cr_ = cosf(rotation[g]);
    float sr_ = sinf(rotation[g]);
    float s1q = scale[2*g]   * scale[2*g];
    float s2q = scale[2*g+1] * scale[2*g+1];
    float c00 = cr_*cr_*s1q + sr_*sr_*s2q + 1e-4f;
    float c01 = cr_*sr_*(s1q - s2q);
    float c11 = sr_*sr_*s1q + cr_*cr_*s2q + 1e-4f;
    // ellipse {dist<=30} extents: |dx| <= sqrt(30*c00), |dy| <= sqrt(30*c11)
    float rx = sqrtf(30.f * c00);
    float ry = sqrtf(30.f * c11);
    float rdet = 1.0f / (c00*c11 - c01*c01);
    GStage st;
    st.q.cx = cx; st.q.cy = cy;
    st.q.A =  K_EXP * c11 * rdet;          // k * inv00
    st.q.B = -2.0f * K_EXP * c01 * rdet;   // 2k * inv01
    st.q.C =  K_EXP * c00 * rdet;          // k * inv11
    float a = alpha[g] * iw[g];
    st.q.cr = a * color[3*g];
    st.q.cg = a * color[3*g+1];
    st.q.cb = a * color[3*g+2];
    st.tx0 = max(0,        (int)floorf((cx - rx) * (1.0f/TILE)));
    st.tx1 = min(TX_N - 1, (int)floorf((cx + rx) * (1.0f/TILE)));
    st.ty0 = max(0,        (int)floorf((cy - ry) * (1.0f/TILE)));
    st.ty1 = min(TY_N - 1, (int)floorf((cy + ry) * (1.0f/TILE)));
    gs[g] = st;
    atomicAdd(&S[0], st.q.cr);
    atomicAdd(&S[1], st.q.cg);
    atomicAdd(&S[2], st.q.cb);
}

// ---------- pass 2: bin gaussians into per-tile slabs (1 wave per gaussian) ----------
__global__ __launch_bounds__(64) void bin_kernel(
    const GStage* __restrict__ gs,
    int* __restrict__ counts,
    char* __restrict__ entries)
{
    const GStage st = gs[blockIdx.x];           // wave-uniform
    const int nx = st.tx1 - st.tx0 + 1;
    const int ny = st.ty1 - st.ty0 + 1;
    const int ntot = nx * ny;
    for (int f = (int)threadIdx.x; f < ntot; f += 64) {
        int tyo = f / nx;
        int txo = f - tyo * nx;
        int t = (st.ty0 + tyo) * TX_N + (st.tx0 + txo);
        int idx = atomicAdd(&counts[t], 1);
        float4* dst = (float4*)(entries + (size_t)t * ENT_STRIDE + (size_t)idx * ENT_BYTES);
        dst[0] = make_float4(st.q.cx, st.q.cy, st.q.A, st.q.B);
        dst[1] = make_float4(st.q.C,  st.q.cr, st.q.cg, st.q.cb);
    }
}

// ---------- pass 3: rasterize one 8x8 tile per 1-wave block, direct stores ----------
__global__ __launch_bounds__(64) void raster_kernel(
    const int* __restrict__ counts,
    const float* __restrict__ S,
    const char* __restrict__ entries,
    float* __restrict__ out)
{
    const int tx = blockIdx.x, ty = blockIdx.y;
    const int t = ty * TX_N + tx;
    const int lane = (int)threadIdx.x;
    const float px = (float)(tx * TILE + (lane & 7));
    const float py = (float)(ty * TILE + (lane >> 3));
    const int n = counts[t];
    const GParam* __restrict__ gp = (const GParam*)(entries + (size_t)t * ENT_STRIDE);

    // exact background: unlisted (and clamped) gaussians contribute exp(-15)*a*c
    float r = W15 * S[0];
    float g = W15 * S[1];
    float b = W15 * S[2];

    for (int i = 0; i < n; ++i) {
        GParam q = gp[i];                       // uniform index -> s_load
        float dx = px - q.cx;
        float dy = py - q.cy;
        float e = fmaf(dx, fmaf(q.A, dx, q.B * dy), q.C * (dy * dy));
        e = fmaxf(e, ELIM);
        float w = __builtin_amdgcn_exp2f(e) - W15;   // cancels background for listed
        r = fmaf(w, q.cr, r);
        g = fmaf(w, q.cg, g);
        b = fmaf(w, q.cb, b);
    }

    const int p = (ty * TILE + (lane >> 3)) * IMG_W + tx * TILE + (lane & 7);
    out[p]          = r;
    out[NPIX + p]   = g;
    out[2*NPIX + p] = b;
}

// ---------- fallback (no ws): dense LDS version with atomics ----------
#define SPLIT 8
#define GPS (NG / SPLIT)
__global__ __launch_bounds__(256) void raster_lds_kernel(
    const float* __restrict__ alpha,
    const float* __restrict__ color,
    const float* __restrict__ offset,
    const float* __restrict__ scale,
    const float* __restrict__ rotation,
    const float* __restrict__ basep,
    const float* __restrict__ iw,
    float* __restrict__ out)
{
    __shared__ GParam gp[GPS];
    const int tid = threadIdx.x;
    if (tid < GPS) {
        const int g = blockIdx.y * GPS + tid;
        float cx = fminf(fmaxf(basep[2*g]   + offset[2*g],   0.f), 224.f);
        float cy = fminf(fmaxf(basep[2*g+1] + offset[2*g+1], 0.f), 224.f);
        float cr_ = cosf(rotation[g]);
        float sr_ = sinf(rotation[g]);
        float s1q = scale[2*g]   * scale[2*g];
        float s2q = scale[2*g+1] * scale[2*g+1];
        float c00 = cr_*cr_*s1q + sr_*sr_*s2q + 1e-4f;
        float c01 = cr_*sr_*(s1q - s2q);
        float c11 = sr_*sr_*s1q + cr_*cr_*s2q + 1e-4f;
        float rdet = 1.0f / (c00*c11 - c01*c01);
        GParam q;
        q.cx = cx; q.cy = cy;
        q.A =  K_EXP * c11 * rdet;
        q.B = -2.0f * K_EXP * c01 * rdet;
        q.C =  K_EXP * c00 * rdet;
        float a = alpha[g] * iw[g];
        q.cr = a * color[3*g];
        q.cg = a * color[3*g+1];
        q.cb = a * color[3*g+2];
        gp[tid] = q;
    }
    __syncthreads();

    const int p = blockIdx.x * 256 + tid;
    const float px = (float)(p % IMG_W);
    const float py = (float)(p / IMG_W);
    float r = 0.f, g = 0.f, b = 0.f;
    #pragma unroll 4
    for (int i = 0; i < GPS; ++i) {
        GParam q = gp[i];
        float dx = px - q.cx;
        float dy = py - q.cy;
        float e = fmaf(dx, fmaf(q.A, dx, q.B * dy), q.C * (dy * dy));
        e = fmaxf(e, ELIM);
        float w = __builtin_amdgcn_exp2f(e);
        r = fmaf(w, q.cr, r);
        g = fmaf(w, q.cg, g);
        b = fmaf(w, q.cb, b);
    }
    atomicAdd(&out[p],          r);
    atomicAdd(&out[NPIX + p],   g);
    atomicAdd(&out[2*NPIX + p], b);
}

extern "C" void kernel_launch(void* const* d_in, const int* in_sizes, int n_in,
                              void* d_out, int out_size, void* d_ws, size_t ws_size,
                              hipStream_t stream)
{
    const float* alpha    = (const float*)d_in[0];
    const float* color    = (const float*)d_in[1];
    const float* offset   = (const float*)d_in[2];
    const float* scale    = (const float*)d_in[3];
    const float* rotation = (const float*)d_in[4];
    const float* basep    = (const float*)d_in[5];
    const float* iw       = (const float*)d_in[6];
    float* out = (float*)d_out;

    if (ws_size >= WS_NEED) {
        float*  S       = (float*)d_ws;
        int*    counts  = (int*)((char*)d_ws + WS_CNT_OFF);
        GStage* gstage  = (GStage*)((char*)d_ws + WS_STAGE_OFF);
        char*   entries = (char*)d_ws + WS_ENT_OFF;

        hipMemsetAsync(d_ws, 0, 4096, stream);  // zero S + counts
        prep_kernel<<<(NG + 255) / 256, 256, 0, stream>>>(
            alpha, color, offset, scale, rotation, basep, iw, gstage, S);
        bin_kernel<<<NG, 64, 0, stream>>>(gstage, counts, entries);
        raster_kernel<<<dim3(TX_N, TY_N), 64, 0, stream>>>(counts, S, entries, out);
    } else {
        hipMemsetAsync(out, 0, (size_t)out_size * sizeof(float), stream);
        dim3 grid(NPIX / 256, SPLIT);
        raster_lds_kernel<<<grid, 256, 0, stream>>>(
            alpha, color, offset, scale, rotation, basep, iw, out);
    }
}

// Round 4
// 91.948 us; speedup vs baseline: 1.1519x; 1.1519x over previous
//
#include <hip/hip_runtime.h>

#define IMG_H 224
#define IMG_W 224
#define NPIX (IMG_H * IMG_W)        // 50176
#define NG 1024
#define SPLIT 8
#define GPS (NG / SPLIT)            // 128 gaussians per slice
#define BX 32                       // block pixel footprint: 32x16 (2 px/thread in x)
#define BY 16
#define NBX (IMG_W / BX)            // 7
#define NBY (IMG_H / BY)            // 14

#define K_EXP  -0.72134752044448170368f   // -0.5 * log2(e)
#define ELIM   -21.640425613334451f       // 30 * K_EXP  (min(dist,30))
#define W15     3.0590232050182579e-07f   // exp(-15) = 2^ELIM

struct __align__(16) GParam { float cx, cy, A, B, C, cr, cg, cb; };

// ws layout: [0,16) float S[4]; [256, 256+16K) int4 bbox[1024]; then GParam[1024]
#define WS_S_OFF     0
#define WS_BBOX_OFF  256
#define WS_PARAM_OFF (WS_BBOX_OFF + NG * 16)
#define WS_NEED      (WS_PARAM_OFF + NG * 32)

// ---------- pass 1: single block, per-gaussian params + px bbox + color sum ----------
__global__ __launch_bounds__(1024) void prep_kernel(
    const float* __restrict__ alpha,
    const float* __restrict__ color,
    const float* __restrict__ offset,
    const float* __restrict__ scale,
    const float* __restrict__ rotation,
    const float* __restrict__ basep,
    const float* __restrict__ iw,
    GParam* __restrict__ params,
    int4* __restrict__ bbox,
    float* __restrict__ S)
{
    const int g = (int)threadIdx.x;           // exactly NG threads
    float cx = fminf(fmaxf(basep[2*g]   + offset[2*g],   0.f), 224.f);
    float cy = fminf(fmaxf(basep[2*g+1] + offset[2*g+1], 0.f), 224.f);
    float cr_ = cosf(rotation[g]);
    float sr_ = sinf(rotation[g]);
    float s1q = scale[2*g]   * scale[2*g];
    float s2q = scale[2*g+1] * scale[2*g+1];
    float c00 = cr_*cr_*s1q + sr_*sr_*s2q + 1e-4f;
    float c01 = cr_*sr_*(s1q - s2q);
    float c11 = sr_*sr_*s1q + cr_*cr_*s2q + 1e-4f;
    // ellipse {dist<=30} extents: |dx| <= sqrt(30*cov00), |dy| <= sqrt(30*cov11)
    float rx = sqrtf(30.f * c00);
    float ry = sqrtf(30.f * c11);
    float rdet = 1.0f / (c00*c11 - c01*c01);
    GParam q;
    q.cx = cx; q.cy = cy;
    q.A =  K_EXP * c11 * rdet;
    q.B = -2.0f * K_EXP * c01 * rdet;
    q.C =  K_EXP * c00 * rdet;
    float a = alpha[g] * iw[g];
    q.cr = a * color[3*g];
    q.cg = a * color[3*g+1];
    q.cb = a * color[3*g+2];
    params[g] = q;
    int4 bb;
    bb.x = (int)floorf(cx - rx);   // x min
    bb.y = (int)ceilf (cx + rx);   // x max
    bb.z = (int)floorf(cy - ry);   // y min
    bb.w = (int)ceilf (cy + ry);   // y max
    bbox[g] = bb;

    // block reduction of (a*cr, a*cg, a*cb) -> S (exact background base)
    float vr = q.cr, vg = q.cg, vb = q.cb;
    #pragma unroll
    for (int o = 32; o >= 1; o >>= 1) {
        vr += __shfl_down(vr, o);
        vg += __shfl_down(vg, o);
        vb += __shfl_down(vb, o);
    }
    __shared__ float sw[16][3];
    const int wid = (int)threadIdx.x >> 6;
    if (((int)threadIdx.x & 63) == 0) { sw[wid][0] = vr; sw[wid][1] = vg; sw[wid][2] = vb; }
    __syncthreads();
    if (threadIdx.x == 0) {
        float tr = 0.f, tg = 0.f, tb = 0.f;
        for (int i = 0; i < 16; ++i) { tr += sw[i][0]; tg += sw[i][1]; tb += sw[i][2]; }
        S[0] = tr; S[1] = tg; S[2] = tb;
    }
}

// ---------- pass 2: raster; scalar bbox scan + exact background, 2 px/thread ----------
__global__ __launch_bounds__(256) void raster_kernel(
    const GParam* __restrict__ params,
    const int4* __restrict__ bbox,
    const float* __restrict__ S,
    float* __restrict__ out)
{
    const int bx0 = blockIdx.x * BX;
    const int by0 = blockIdx.y * BY;
    const int base = blockIdx.z * GPS;
    const int tid = (int)threadIdx.x;
    const int lx = (tid & 15) << 1;       // 0,2,..,30
    const int ly = tid >> 4;              // 0..15
    const float px = (float)(bx0 + lx);
    const float py = (float)(by0 + ly);

    float r0, g0, b0, r1, g1, b1;
    if (blockIdx.z == 0) {                // slice 0 carries the exact background
        float s0 = S[0], s1 = S[1], s2 = S[2];
        r0 = W15 * s0; g0 = W15 * s1; b0 = W15 * s2;
        r1 = r0; g1 = g0; b1 = b0;
    } else {
        r0 = g0 = b0 = r1 = g1 = b1 = 0.f;
    }

    const int bx1 = bx0 + BX - 1, by1 = by0 + BY - 1;
    for (int i = 0; i < GPS; ++i) {
        const int4 bb = bbox[base + i];                  // uniform -> s_load, SALU test
        if (bb.x <= bx1 && bb.y >= bx0 && bb.z <= by1 && bb.w >= by0) {
            GParam q = params[base + i];                 // uniform -> s_load
            float dy  = py - q.cy;
            float t   = q.B * dy;
            float w2  = q.C * (dy * dy);
            float dx0 = px - q.cx;
            float u0  = fmaf(q.A, dx0, t);
            float e0  = fmaf(dx0, u0, w2);
            float u1  = u0 + q.A;
            float e1  = fmaf(dx0 + 1.0f, u1, w2);
            e0 = fmaxf(e0, ELIM);
            e1 = fmaxf(e1, ELIM);
            float w0 = __builtin_amdgcn_exp2f(e0) - W15; // cancels background exactly
            float w1 = __builtin_amdgcn_exp2f(e1) - W15;
            r0 = fmaf(w0, q.cr, r0);  r1 = fmaf(w1, q.cr, r1);
            g0 = fmaf(w0, q.cg, g0);  g1 = fmaf(w1, q.cg, g1);
            b0 = fmaf(w0, q.cb, b0);  b1 = fmaf(w1, q.cb, b1);
        }
    }

    const int p0 = (by0 + ly) * IMG_W + bx0 + lx;
    atomicAdd(&out[p0],            r0);  atomicAdd(&out[p0 + 1],            r1);
    atomicAdd(&out[NPIX + p0],     g0);  atomicAdd(&out[NPIX + p0 + 1],     g1);
    atomicAdd(&out[2*NPIX + p0],   b0);  atomicAdd(&out[2*NPIX + p0 + 1],   b1);
}

// ---------- fallback (ws too small): dense LDS version with atomics ----------
__global__ __launch_bounds__(256) void raster_lds_kernel(
    const float* __restrict__ alpha,
    const float* __restrict__ color,
    const float* __restrict__ offset,
    const float* __restrict__ scale,
    const float* __restrict__ rotation,
    const float* __restrict__ basep,
    const float* __restrict__ iw,
    float* __restrict__ out)
{
    __shared__ GParam gp[GPS];
    const int tid = (int)threadIdx.x;
    if (tid < GPS) {
        const int g = blockIdx.y * GPS + tid;
        float cx = fminf(fmaxf(basep[2*g]   + offset[2*g],   0.f), 224.f);
        float cy = fminf(fmaxf(basep[2*g+1] + offset[2*g+1], 0.f), 224.f);
        float cr_ = cosf(rotation[g]);
        float sr_ = sinf(rotation[g]);
        float s1q = scale[2*g]   * scale[2*g];
        float s2q = scale[2*g+1] * scale[2*g+1];
        float c00 = cr_*cr_*s1q + sr_*sr_*s2q + 1e-4f;
        float c01 = cr_*sr_*(s1q - s2q);
        float c11 = sr_*sr_*s1q + cr_*cr_*s2q + 1e-4f;
        float rdet = 1.0f / (c00*c11 - c01*c01);
        GParam q;
        q.cx = cx; q.cy = cy;
        q.A =  K_EXP * c11 * rdet;
        q.B = -2.0f * K_EXP * c01 * rdet;
        q.C =  K_EXP * c00 * rdet;
        float a = alpha[g] * iw[g];
        q.cr = a * color[3*g];
        q.cg = a * color[3*g+1];
        q.cb = a * color[3*g+2];
        gp[tid] = q;
    }
    __syncthreads();

    const int p = blockIdx.x * 256 + tid;
    const float px = (float)(p % IMG_W);
    const float py = (float)(p / IMG_W);
    float r = 0.f, g = 0.f, b = 0.f;
    #pragma unroll 4
    for (int i = 0; i < GPS; ++i) {
        GParam q = gp[i];
        float dx = px - q.cx;
        float dy = py - q.cy;
        float e = fmaf(dx, fmaf(q.A, dx, q.B * dy), q.C * (dy * dy));
        e = fmaxf(e, ELIM);
        float w = __builtin_amdgcn_exp2f(e);
        r = fmaf(w, q.cr, r);
        g = fmaf(w, q.cg, g);
        b = fmaf(w, q.cb, b);
    }
    atomicAdd(&out[p],          r);
    atomicAdd(&out[NPIX + p],   g);
    atomicAdd(&out[2*NPIX + p], b);
}

extern "C" void kernel_launch(void* const* d_in, const int* in_sizes, int n_in,
                              void* d_out, int out_size, void* d_ws, size_t ws_size,
                              hipStream_t stream)
{
    const float* alpha    = (const float*)d_in[0];
    const float* color    = (const float*)d_in[1];
    const float* offset   = (const float*)d_in[2];
    const float* scale    = (const float*)d_in[3];
    const float* rotation = (const float*)d_in[4];
    const float* basep    = (const float*)d_in[5];
    const float* iw       = (const float*)d_in[6];
    float* out = (float*)d_out;

    hipMemsetAsync(out, 0, (size_t)out_size * sizeof(float), stream);

    if (ws_size >= WS_NEED) {
        float*  S      = (float*)((char*)d_ws + WS_S_OFF);
        int4*   bbox   = (int4*)((char*)d_ws + WS_BBOX_OFF);
        GParam* params = (GParam*)((char*)d_ws + WS_PARAM_OFF);

        prep_kernel<<<1, 1024, 0, stream>>>(
            alpha, color, offset, scale, rotation, basep, iw, params, bbox, S);
        raster_kernel<<<dim3(NBX, NBY, SPLIT), 256, 0, stream>>>(
            params, bbox, S, out);
    } else {
        dim3 grid(NPIX / 256, SPLIT);
        raster_lds_kernel<<<grid, 256, 0, stream>>>(
            alpha, color, offset, scale, rotation, basep, iw, out);
    }
}